// Round 12
// baseline (70.822 us; speedup 1.0000x reference)
//
#include <hip/hip_runtime.h>
#include <hip/hip_fp16.h>

#define N_NODES 100000
#define N_EDGES 1600000
#define F_IN    128
#define F_OUT   32

#define BKT_SHIFT  7
#define BKT_SIZE   128
#define NBKT       782          // ceil(100000/128)
#define BKT_STRIDE 2560         // mean 2046 per bucket, +11 sigma headroom

#define BIN_THREADS 512
#define BIN_TILE    8192
#define EPT         (BIN_TILE / BIN_THREADS)               // 16
#define NTILES      ((N_EDGES + BIN_TILE - 1) / BIN_TILE)  // 196

typedef _Float16 f16x8 __attribute__((ext_vector_type(8)));
typedef float    f32x4 __attribute__((ext_vector_type(4)));

// Bin edges by dst>>7 into 782 buckets. Rank-capture: one LDS atomic per edge
// gives both the histogram and the in-tile rank; 8192-edge tiles make
// same-bucket runs ~10 edges -> mostly full-line global writes.
__global__ __launch_bounds__(BIN_THREADS) void bin_kernel(const int* __restrict__ ei,
                                                          int* __restrict__ gcur,
                                                          unsigned int* __restrict__ binned) {
    __shared__ int cnt[NBKT], gbase[NBKT];
    int t = threadIdx.x;
    for (int b = t; b < NBKT; b += BIN_THREADS) cnt[b] = 0;
    __syncthreads();
    int ebase = blockIdx.x * BIN_TILE;
    unsigned int pk[EPT];
    int rk[EPT];
    short bkt[EPT];
#pragma unroll
    for (int k = 0; k < EPT; ++k) {
        int e = ebase + k * BIN_THREADS + t;
        if (e < N_EDGES) {
            int s = ei[e];
            int d = ei[N_EDGES + e];
            bkt[k] = (short)(d >> BKT_SHIFT);
            pk[k]  = (unsigned)s | ((unsigned)(d & (BKT_SIZE - 1)) << 25);
            rk[k]  = atomicAdd(&cnt[bkt[k]], 1);
        } else {
            bkt[k] = -1;
        }
    }
    __syncthreads();
    for (int b = t; b < NBKT; b += BIN_THREADS)
        if (cnt[b] > 0) gbase[b] = atomicAdd(&gcur[b], cnt[b]);
    __syncthreads();
#pragma unroll
    for (int k = 0; k < EPT; ++k) {
        if (bkt[k] >= 0) {
            int p = gbase[bkt[k]] + rk[k];
            if (p < BKT_STRIDE)
                binned[(size_t)bkt[k] * BKT_STRIDE + p] = pk[k];
        }
    }
}

// Fused: per-bucket degree histogram (-> dinv in LDS) + MFMA matmul for the
// bucket's 128 rows. hs = fp16( (x @ W) * dinv[row] ).
// 512 threads = 8 waves of 16 rows; A-frags straight from global (coalesced);
// W transposed once into LDS.
#define WH_STRIDE 136   // halfs per W column (272 B -> conflict-free b128)
__global__ __launch_bounds__(512) void matmul_kernel(const float4* __restrict__ x4,
                                                     const float* __restrict__ W,
                                                     const unsigned int* __restrict__ binned,
                                                     const int* __restrict__ gcur,
                                                     __half* __restrict__ hs) {
    __shared__ _Float16 Wh[F_OUT * WH_STRIDE];   // 8.7 KB, [col][k]
    __shared__ int cnt128[BKT_SIZE];
    __shared__ float dinvL[BKT_SIZE];
    int t = threadIdx.x;
    int b = blockIdx.x;

    if (t < BKT_SIZE) cnt128[t] = 0;
    {
        int col = t & 31, kb = (t >> 5) * 8;
        for (int u = 0; u < 8; ++u)
            Wh[col * WH_STRIDE + kb + u] = (_Float16)W[(kb + u) * F_OUT + col];
    }
    __syncthreads();

    int ne = gcur[b];
    if (ne > BKT_STRIDE) ne = BKT_STRIDE;
    const unsigned int* eb = binned + (size_t)b * BKT_STRIDE;
    for (int i = t; i < ne; i += 512)
        atomicAdd(&cnt128[eb[i] >> 25], 1);
    __syncthreads();
    if (t < BKT_SIZE) dinvL[t] = rsqrtf((float)(cnt128[t] + 1));  // +1 self loop
    __syncthreads();

    int w = t >> 6, l = t & 63;
    int lr = l & 15, kg = l >> 4;                // A row lane, k-group
    int row = b * 128 + w * 16 + lr;
    const float4* xr = x4 + (size_t)row * 32;
    bool rok = row < N_NODES;

    f16x8 a[4];
#pragma unroll
    for (int ks = 0; ks < 4; ++ks) {
        float4 v0, v1;
        if (rok) {
            v0 = xr[ks * 8 + kg * 2];
            v1 = xr[ks * 8 + kg * 2 + 1];
        } else {
            v0 = make_float4(0, 0, 0, 0);
            v1 = v0;
        }
        f16x8 av;
        av[0] = (_Float16)v0.x; av[1] = (_Float16)v0.y;
        av[2] = (_Float16)v0.z; av[3] = (_Float16)v0.w;
        av[4] = (_Float16)v1.x; av[5] = (_Float16)v1.y;
        av[6] = (_Float16)v1.z; av[7] = (_Float16)v1.w;
        a[ks] = av;
    }

    f32x4 c0 = {0.f, 0.f, 0.f, 0.f}, c1 = {0.f, 0.f, 0.f, 0.f};
#pragma unroll
    for (int ks = 0; ks < 4; ++ks) {
        f16x8 b0 = *(const f16x8*)&Wh[lr * WH_STRIDE + ks * 32 + kg * 8];
        f16x8 b1 = *(const f16x8*)&Wh[(16 + lr) * WH_STRIDE + ks * 32 + kg * 8];
        c0 = __builtin_amdgcn_mfma_f32_16x16x32_f16(a[ks], b0, c0, 0, 0, 0);
        c1 = __builtin_amdgcn_mfma_f32_16x16x32_f16(a[ks], b1, c1, 0, 0, 0);
    }

    // D layout: col = lane&15, row = (lane>>4)*4 + i   [m89-verified]
    int lrow0 = w * 16 + kg * 4;
#pragma unroll
    for (int i = 0; i < 4; ++i) {
        int orow = b * 128 + lrow0 + i;
        if (orow < N_NODES) {
            float dv = dinvL[lrow0 + i];
            hs[(size_t)orow * F_OUT + lr]      = (__half)(c0[i] * dv);
            hs[(size_t)orow * F_OUT + 16 + lr] = (__half)(c1[i] * dv);
        }
    }
}

__device__ inline void acc8(uint4 u, float* a) {
    float2 f0 = __half22float2(*(__half2*)&u.x);
    float2 f1 = __half22float2(*(__half2*)&u.y);
    float2 f2 = __half22float2(*(__half2*)&u.z);
    float2 f3 = __half22float2(*(__half2*)&u.w);
    a[0] += f0.x; a[1] += f0.y; a[2] += f1.x; a[3] += f1.y;
    a[4] += f2.x; a[5] += f2.y; a[6] += f3.x; a[7] += f3.y;
}

// One 512-thread block per bucket: single eb read, rank-capture counting sort,
// then 4 lanes/node x 16B half8 gathers, 8-deep unrolled.
#define AEPT 5   // ceil(2560/512)
__global__ __launch_bounds__(512) void aggregate_kernel(const unsigned int* __restrict__ binned,
                                                        const int* __restrict__ gcur,
                                                        const uint4* __restrict__ hs8,
                                                        const float* __restrict__ bias,
                                                        float* __restrict__ out) {
    __shared__ int cnt[BKT_SIZE];
    __shared__ int sc[BKT_SIZE];
    __shared__ int rp[BKT_SIZE + 1];
    __shared__ int se[BKT_STRIDE];       // 10 KB
    int t = threadIdx.x;
    int b = blockIdx.x;
    int ne = gcur[b];
    if (ne > BKT_STRIDE) ne = BKT_STRIDE;
    const unsigned int* eb = binned + (size_t)b * BKT_STRIDE;

    if (t < BKT_SIZE) cnt[t] = 0;
    __syncthreads();

    unsigned pk[AEPT];
    int rk[AEPT];
#pragma unroll
    for (int k = 0; k < AEPT; ++k) {
        int i = t + k * 512;
        pk[k] = (i < ne) ? eb[i] : 0xFFFFFFFFu;
    }
#pragma unroll
    for (int k = 0; k < AEPT; ++k) {
        rk[k] = -1;
        if (pk[k] != 0xFFFFFFFFu)
            rk[k] = atomicAdd(&cnt[pk[k] >> 25], 1);
    }
    __syncthreads();
    int v = (t < BKT_SIZE) ? cnt[t] : 0;
    if (t < BKT_SIZE) sc[t] = v;
    __syncthreads();
    for (int off = 1; off < BKT_SIZE; off <<= 1) {
        int add = (t < BKT_SIZE && t >= off) ? sc[t - off] : 0;
        __syncthreads();
        if (t < BKT_SIZE) sc[t] += add;
        __syncthreads();
    }
    if (t < BKT_SIZE) rp[t] = sc[t] - v;     // exclusive prefix
    if (t == 0) rp[BKT_SIZE] = ne;
    __syncthreads();
#pragma unroll
    for (int k = 0; k < AEPT; ++k) {
        if (rk[k] >= 0) {
            int pos = rp[pk[k] >> 25] + rk[k];   // < ne <= BKT_STRIDE always
            se[pos] = (int)(pk[k] & 0x1FFFFFF);
        }
    }
    __syncthreads();

    int n = t >> 2, q = t & 3;           // 128 nodes x 4 lanes (8 cols/lane)
    int gnode = b * BKT_SIZE + n;
    if (gnode >= N_NODES) return;
    int beg = rp[n], end = rp[n + 1];
    int deg = end - beg;
    float acc[8] = {0.f, 0.f, 0.f, 0.f, 0.f, 0.f, 0.f, 0.f};
    int p = beg;
    for (; p + 7 < end; p += 8) {        // 8 independent 16B gathers in flight
        uint4 u0 = hs8[(size_t)se[p]     * 4 + q];
        uint4 u1 = hs8[(size_t)se[p + 1] * 4 + q];
        uint4 u2 = hs8[(size_t)se[p + 2] * 4 + q];
        uint4 u3 = hs8[(size_t)se[p + 3] * 4 + q];
        uint4 u4 = hs8[(size_t)se[p + 4] * 4 + q];
        uint4 u5 = hs8[(size_t)se[p + 5] * 4 + q];
        uint4 u6 = hs8[(size_t)se[p + 6] * 4 + q];
        uint4 u7 = hs8[(size_t)se[p + 7] * 4 + q];
        acc8(u0, acc); acc8(u1, acc); acc8(u2, acc); acc8(u3, acc);
        acc8(u4, acc); acc8(u5, acc); acc8(u6, acc); acc8(u7, acc);
    }
    for (; p + 3 < end; p += 4) {
        uint4 u0 = hs8[(size_t)se[p]     * 4 + q];
        uint4 u1 = hs8[(size_t)se[p + 1] * 4 + q];
        uint4 u2 = hs8[(size_t)se[p + 2] * 4 + q];
        uint4 u3 = hs8[(size_t)se[p + 3] * 4 + q];
        acc8(u0, acc); acc8(u1, acc); acc8(u2, acc); acc8(u3, acc);
    }
    for (; p < end; ++p)
        acc8(hs8[(size_t)se[p] * 4 + q], acc);

    float dv = rsqrtf((float)(deg + 1));     // same value matmul folded for src
    uint4 us = hs8[(size_t)gnode * 4 + q];
    float selfv[8];
    {
        float2 f0 = __half22float2(*(__half2*)&us.x);
        float2 f1 = __half22float2(*(__half2*)&us.y);
        float2 f2 = __half22float2(*(__half2*)&us.z);
        float2 f3 = __half22float2(*(__half2*)&us.w);
        selfv[0] = f0.x; selfv[1] = f0.y; selfv[2] = f1.x; selfv[3] = f1.y;
        selfv[4] = f2.x; selfv[5] = f2.y; selfv[6] = f3.x; selfv[7] = f3.y;
    }
    float4 bv0 = *(const float4*)&bias[q * 8];
    float4 bv1 = *(const float4*)&bias[q * 8 + 4];
    float4 o0, o1;
    o0.x = bv0.x + dv * (acc[0] + selfv[0]);
    o0.y = bv0.y + dv * (acc[1] + selfv[1]);
    o0.z = bv0.z + dv * (acc[2] + selfv[2]);
    o0.w = bv0.w + dv * (acc[3] + selfv[3]);
    o1.x = bv1.x + dv * (acc[4] + selfv[4]);
    o1.y = bv1.y + dv * (acc[5] + selfv[5]);
    o1.z = bv1.z + dv * (acc[6] + selfv[6]);
    o1.w = bv1.w + dv * (acc[7] + selfv[7]);
    *(float4*)&out[(size_t)gnode * F_OUT + q * 8]     = o0;
    *(float4*)&out[(size_t)gnode * F_OUT + q * 8 + 4] = o1;
}

extern "C" void kernel_launch(void* const* d_in, const int* in_sizes, int n_in,
                              void* d_out, int out_size, void* d_ws, size_t ws_size,
                              hipStream_t stream) {
    const float* x  = (const float*)d_in[0];
    const int*   ei = (const int*)d_in[1];   // int32 on device
    const float* W  = (const float*)d_in[2];
    const float* b  = (const float*)d_in[3];
    float* out = (float*)d_out;

    int*          gcur   = (int*)d_ws;                       // pad to 1024
    unsigned int* binned = (unsigned int*)(gcur + 1024);     // NBKT*BKT_STRIDE ~8 MB
    __half*       hs     = (__half*)(binned + (size_t)NBKT * BKT_STRIDE);  // 6.4 MB

    hipMemsetAsync(gcur, 0, NBKT * sizeof(int), stream);

    bin_kernel<<<NTILES, BIN_THREADS, 0, stream>>>(ei, gcur, binned);

    matmul_kernel<<<NBKT, 512, 0, stream>>>((const float4*)x, W, binned, gcur, hs);

    aggregate_kernel<<<NBKT, 512, 0, stream>>>(binned, gcur, (const uint4*)hs, b, out);
}

// Round 13
// 70.276 us; speedup vs baseline: 1.0078x; 1.0078x over previous
//
#include <hip/hip_runtime.h>
#include <hip/hip_fp16.h>

#define N_NODES 100000
#define N_EDGES 1600000
#define F_IN    128
#define F_OUT   32

#define BKT_SHIFT  7
#define BKT_SIZE   128
#define NBKT       782          // ceil(100000/128)
#define BKT_STRIDE 2560         // mean 2046 per bucket, +11 sigma headroom

#define BIN_THREADS 512
#define BIN_TILE    8192
#define EPT         (BIN_TILE / BIN_THREADS)               // 16
#define NTILES      ((N_EDGES + BIN_TILE - 1) / BIN_TILE)  // 196

#define AGG_SPLIT  4
#define SUB        32           // nodes per aggregate block
#define SUB_STRIDE 768          // mean 512/sub-bucket, +11 sigma headroom

typedef _Float16 f16x8 __attribute__((ext_vector_type(8)));
typedef float    f32x4 __attribute__((ext_vector_type(4)));

// Bin edges by dst>>7 into 782 buckets. Rank-capture: one LDS atomic per edge
// gives both the histogram and the in-tile rank; 8192-edge tiles make
// same-bucket runs ~10 edges -> mostly full-line global writes.
__global__ __launch_bounds__(BIN_THREADS) void bin_kernel(const int* __restrict__ ei,
                                                          int* __restrict__ gcur,
                                                          unsigned int* __restrict__ binned) {
    __shared__ int cnt[NBKT], gbase[NBKT];
    int t = threadIdx.x;
    for (int b = t; b < NBKT; b += BIN_THREADS) cnt[b] = 0;
    __syncthreads();
    int ebase = blockIdx.x * BIN_TILE;
    unsigned int pk[EPT];
    int rk[EPT];
    short bkt[EPT];
#pragma unroll
    for (int k = 0; k < EPT; ++k) {
        int e = ebase + k * BIN_THREADS + t;
        if (e < N_EDGES) {
            int s = ei[e];
            int d = ei[N_EDGES + e];
            bkt[k] = (short)(d >> BKT_SHIFT);
            pk[k]  = (unsigned)s | ((unsigned)(d & (BKT_SIZE - 1)) << 25);
            rk[k]  = atomicAdd(&cnt[bkt[k]], 1);
        } else {
            bkt[k] = -1;
        }
    }
    __syncthreads();
    for (int b = t; b < NBKT; b += BIN_THREADS)
        if (cnt[b] > 0) gbase[b] = atomicAdd(&gcur[b], cnt[b]);
    __syncthreads();
#pragma unroll
    for (int k = 0; k < EPT; ++k) {
        if (bkt[k] >= 0) {
            int p = gbase[bkt[k]] + rk[k];
            if (p < BKT_STRIDE)
                binned[(size_t)bkt[k] * BKT_STRIDE + p] = pk[k];
        }
    }
}

// Fused: per-bucket degree histogram (-> dinv in LDS) + MFMA matmul for the
// bucket's 128 rows. hs = fp16( (x @ W) * dinv[row] ).
// x loads issued BEFORE the histogram so HBM latency hides under it.
#define WH_STRIDE 136   // halfs per W column (272 B -> conflict-free b128)
__global__ __launch_bounds__(512) void matmul_kernel(const float4* __restrict__ x4,
                                                     const float* __restrict__ W,
                                                     const unsigned int* __restrict__ binned,
                                                     const int* __restrict__ gcur,
                                                     __half* __restrict__ hs) {
    __shared__ _Float16 Wh[F_OUT * WH_STRIDE];   // 8.7 KB, [col][k]
    __shared__ int cnt128[BKT_SIZE];
    __shared__ float dinvL[BKT_SIZE];
    int t = threadIdx.x;
    int b = blockIdx.x;

    if (t < BKT_SIZE) cnt128[t] = 0;
    {
        int col = t & 31, kb = (t >> 5) * 8;
        for (int u = 0; u < 8; ++u)
            Wh[col * WH_STRIDE + kb + u] = (_Float16)W[(kb + u) * F_OUT + col];
    }

    int w = t >> 6, l = t & 63;
    int lr = l & 15, kg = l >> 4;                // A row lane, k-group
    int row = b * 128 + w * 16 + lr;
    const float4* xr = x4 + (size_t)row * 32;
    bool rok = row < N_NODES;

    // issue the 8 x loads now; they stay in flight across the histogram
    float4 v0[4], v1[4];
#pragma unroll
    for (int ks = 0; ks < 4; ++ks) {
        if (rok) {
            v0[ks] = xr[ks * 8 + kg * 2];
            v1[ks] = xr[ks * 8 + kg * 2 + 1];
        } else {
            v0[ks] = make_float4(0, 0, 0, 0);
            v1[ks] = v0[ks];
        }
    }
    __syncthreads();   // cnt128 zero + Wh staged

    int ne = gcur[b];
    if (ne > BKT_STRIDE) ne = BKT_STRIDE;
    const unsigned int* eb = binned + (size_t)b * BKT_STRIDE;
    for (int i = t; i < ne; i += 512)
        atomicAdd(&cnt128[eb[i] >> 25], 1);
    __syncthreads();
    if (t < BKT_SIZE) dinvL[t] = rsqrtf((float)(cnt128[t] + 1));  // +1 self loop
    __syncthreads();

    f16x8 a[4];
#pragma unroll
    for (int ks = 0; ks < 4; ++ks) {
        f16x8 av;
        av[0] = (_Float16)v0[ks].x; av[1] = (_Float16)v0[ks].y;
        av[2] = (_Float16)v0[ks].z; av[3] = (_Float16)v0[ks].w;
        av[4] = (_Float16)v1[ks].x; av[5] = (_Float16)v1[ks].y;
        av[6] = (_Float16)v1[ks].z; av[7] = (_Float16)v1[ks].w;
        a[ks] = av;
    }

    f32x4 c0 = {0.f, 0.f, 0.f, 0.f}, c1 = {0.f, 0.f, 0.f, 0.f};
#pragma unroll
    for (int ks = 0; ks < 4; ++ks) {
        f16x8 b0 = *(const f16x8*)&Wh[lr * WH_STRIDE + ks * 32 + kg * 8];
        f16x8 b1 = *(const f16x8*)&Wh[(16 + lr) * WH_STRIDE + ks * 32 + kg * 8];
        c0 = __builtin_amdgcn_mfma_f32_16x16x32_f16(a[ks], b0, c0, 0, 0, 0);
        c1 = __builtin_amdgcn_mfma_f32_16x16x32_f16(a[ks], b1, c1, 0, 0, 0);
    }

    // D layout: col = lane&15, row = (lane>>4)*4 + i   [m89-verified]
    int lrow0 = w * 16 + kg * 4;
#pragma unroll
    for (int i = 0; i < 4; ++i) {
        int orow = b * 128 + lrow0 + i;
        if (orow < N_NODES) {
            float dv = dinvL[lrow0 + i];
            hs[(size_t)orow * F_OUT + lr]      = (__half)(c0[i] * dv);
            hs[(size_t)orow * F_OUT + 16 + lr] = (__half)(c1[i] * dv);
        }
    }
}

__device__ inline void acc4(uint2 u, float& a0, float& a1, float& a2, float& a3) {
    float2 f0 = __half22float2(*(__half2*)&u.x);
    float2 f1 = __half22float2(*(__half2*)&u.y);
    a0 += f0.x; a1 += f0.y; a2 += f1.x; a3 += f1.y;
}

// 4 blocks per bucket, 32 nodes each (grid 3128). Rank-capture counting sort,
// degree-balanced wave assignment (nodes sorted by degree so each wave's 8
// nodes have similar edge counts), then 8 lanes/node x 8B gathers, 8-deep.
__global__ __launch_bounds__(256) void aggregate_kernel(const unsigned int* __restrict__ binned,
                                                        const int* __restrict__ gcur,
                                                        const uint2* __restrict__ hs4,
                                                        const float* __restrict__ bias,
                                                        float* __restrict__ out) {
    __shared__ int cnt[SUB];
    __shared__ int sc[SUB];
    __shared__ int rp[SUB + 1];
    __shared__ int order[SUB];
    __shared__ int se[SUB_STRIDE];       // 3 KB
    int t = threadIdx.x;
    int b   = blockIdx.x >> 2;           // bucket
    int sub = blockIdx.x & 3;            // quarter of the bucket
    int ne = gcur[b];
    if (ne > BKT_STRIDE) ne = BKT_STRIDE;
    const unsigned int* eb = binned + (size_t)b * BKT_STRIDE;

    if (t < SUB) cnt[t] = 0;
    __syncthreads();

    unsigned pk[10];
    int rk[10];
#pragma unroll
    for (int k = 0; k < 10; ++k) {
        int i = t + k * 256;
        pk[k] = (i < ne) ? eb[i] : 0xFFFFFFFFu;
    }
#pragma unroll
    for (int k = 0; k < 10; ++k) {
        rk[k] = -1;
        if (pk[k] != 0xFFFFFFFFu) {
            int dl = (int)(pk[k] >> 25);
            if ((dl >> 5) == sub) rk[k] = atomicAdd(&cnt[dl & 31], 1);
        }
    }
    __syncthreads();
    int v = (t < SUB) ? cnt[t] : 0;
    if (t < SUB) sc[t] = v;
    __syncthreads();
    for (int off = 1; off < SUB; off <<= 1) {
        int add = (t < SUB && t >= off) ? sc[t - off] : 0;
        __syncthreads();
        if (t < SUB) sc[t] += add;
        __syncthreads();
    }
    if (t < SUB) {
        int ex = sc[t] - v;              // exclusive prefix
        rp[t] = (ex < SUB_STRIDE) ? ex : SUB_STRIDE;
        // degree-rank permutation: r = #nodes with (deg, idx) greater
        int d = v, r = 0;
#pragma unroll 8
        for (int j = 0; j < SUB; ++j) {
            int dj = cnt[j];
            r += (dj > d) || (dj == d && j < t);
        }
        order[r] = t;
    }
    if (t == 0) {
        int tot = sc[SUB - 1];
        rp[SUB] = (tot > SUB_STRIDE) ? SUB_STRIDE : tot;
    }
    __syncthreads();
#pragma unroll
    for (int k = 0; k < 10; ++k) {
        if (rk[k] >= 0) {
            int dl = (int)(pk[k] >> 25);
            int pos = rp[dl & 31] + rk[k];
            if (pos < SUB_STRIDE) se[pos] = (int)(pk[k] & 0x1FFFFFF);
        }
    }
    __syncthreads();

    int g = t >> 3, j4 = t & 7;          // 32 groups x 8 lanes (4 cols/lane)
    int n = order[g];                    // degree-balanced assignment
    int gnode = b * BKT_SIZE + sub * SUB + n;
    if (gnode >= N_NODES) return;
    float4 bv = *(const float4*)&bias[j4 * 4];
    int deg = cnt[n];
    int beg = rp[n];
    int end = rp[n + 1];
    if (beg + deg < end) end = beg + deg;
    float a0 = 0.f, a1 = 0.f, a2 = 0.f, a3 = 0.f;
    int p = beg;
    for (; p + 7 < end; p += 8) {        // 8 independent 8B gathers in flight
        uint2 u0 = hs4[(size_t)se[p]     * 8 + j4];
        uint2 u1 = hs4[(size_t)se[p + 1] * 8 + j4];
        uint2 u2 = hs4[(size_t)se[p + 2] * 8 + j4];
        uint2 u3 = hs4[(size_t)se[p + 3] * 8 + j4];
        uint2 u4 = hs4[(size_t)se[p + 4] * 8 + j4];
        uint2 u5 = hs4[(size_t)se[p + 5] * 8 + j4];
        uint2 u6 = hs4[(size_t)se[p + 6] * 8 + j4];
        uint2 u7 = hs4[(size_t)se[p + 7] * 8 + j4];
        acc4(u0, a0, a1, a2, a3); acc4(u1, a0, a1, a2, a3);
        acc4(u2, a0, a1, a2, a3); acc4(u3, a0, a1, a2, a3);
        acc4(u4, a0, a1, a2, a3); acc4(u5, a0, a1, a2, a3);
        acc4(u6, a0, a1, a2, a3); acc4(u7, a0, a1, a2, a3);
    }
    for (; p + 3 < end; p += 4) {
        uint2 u0 = hs4[(size_t)se[p]     * 8 + j4];
        uint2 u1 = hs4[(size_t)se[p + 1] * 8 + j4];
        uint2 u2 = hs4[(size_t)se[p + 2] * 8 + j4];
        uint2 u3 = hs4[(size_t)se[p + 3] * 8 + j4];
        acc4(u0, a0, a1, a2, a3); acc4(u1, a0, a1, a2, a3);
        acc4(u2, a0, a1, a2, a3); acc4(u3, a0, a1, a2, a3);
    }
    for (; p < end; ++p) {
        uint2 u0 = hs4[(size_t)se[p] * 8 + j4];
        acc4(u0, a0, a1, a2, a3);
    }
    float dv = rsqrtf((float)(deg + 1));   // same value matmul folded for src
    uint2 us = hs4[(size_t)gnode * 8 + j4];
    float2 s0 = __half22float2(*(__half2*)&us.x);
    float2 s1 = __half22float2(*(__half2*)&us.y);
    float4 o;
    o.x = bv.x + dv * (a0 + s0.x);
    o.y = bv.y + dv * (a1 + s0.y);
    o.z = bv.z + dv * (a2 + s1.x);
    o.w = bv.w + dv * (a3 + s1.y);
    *(float4*)&out[(size_t)gnode * F_OUT + j4 * 4] = o;
}

extern "C" void kernel_launch(void* const* d_in, const int* in_sizes, int n_in,
                              void* d_out, int out_size, void* d_ws, size_t ws_size,
                              hipStream_t stream) {
    const float* x  = (const float*)d_in[0];
    const int*   ei = (const int*)d_in[1];   // int32 on device
    const float* W  = (const float*)d_in[2];
    const float* b  = (const float*)d_in[3];
    float* out = (float*)d_out;

    int*          gcur   = (int*)d_ws;                       // pad to 1024
    unsigned int* binned = (unsigned int*)(gcur + 1024);     // NBKT*BKT_STRIDE ~8 MB
    __half*       hs     = (__half*)(binned + (size_t)NBKT * BKT_STRIDE);  // 6.4 MB

    hipMemsetAsync(gcur, 0, NBKT * sizeof(int), stream);

    bin_kernel<<<NTILES, BIN_THREADS, 0, stream>>>(ei, gcur, binned);

    matmul_kernel<<<NBKT, 512, 0, stream>>>((const float4*)x, W, binned, gcur, hs);

    aggregate_kernel<<<NBKT * AGG_SPLIT, 256, 0, stream>>>(binned, gcur, (const uint2*)hs, b, out);
}